// Round 2
// baseline (22763.123 us; speedup 1.0000x reference)
//
#include <hip/hip_runtime.h>
#include <hip/hip_bf16.h>

// LSTM 2-layer, S=512 B=64 IN=H=1024, fp32 I/O, fp16 MFMA compute.
// Strategy: persistent kernel, 256 wgs (1/CU) x 256 thr (4 waves).
//   z[64,4096] = [x_t | h] (64x2048) @ Wcat^T  per step, K split across 4 waves.
//   Weight rows reordered: p = j*4+g  (j = h-col, g = i,f,g,o) so each wg owns
//   4 h-cols (16 gate rows) and does the elementwise update locally; c in regs.
//   Global barrier: padded flag array, release store + all-to-all poll.
//   Waves 0/1 (x-operand, no recurrent dep) skip the per-step poll.

#define SEQ   512
#define BATCH 64
#define HID   1024
#define NG    4096           // 4*HID
#define KCAT  2048           // IN + HID

typedef __attribute__((ext_vector_type(8))) _Float16 f16x8;
typedef __attribute__((ext_vector_type(4))) float    f32x4;

__device__ __forceinline__ float sigm_f(float x){ return 1.f/(1.f + __expf(-x)); }
__device__ __forceinline__ float tanh_f(float x){
    float e = __expf(-2.f*fabsf(x));
    float r = (1.f - e)/(1.f + e);
    return copysignf(r, x);
}

// ---------------- prep kernels ----------------

__global__ void prep_w_kernel(const float* __restrict__ Wx, const float* __restrict__ Wh,
                              const float* __restrict__ bx, const float* __restrict__ bh,
                              _Float16* __restrict__ Wr, float* __restrict__ br){
    int p = blockIdx.x;            // 0..4095 reordered row
    int j = p >> 2, g = p & 3;
    int r = g*1024 + j;            // original row in Wx/Wh
    int k = threadIdx.x * 8;       // 0..2040
    const float* s = (k < 1024) ? (Wx + (size_t)r*1024 + k)
                                : (Wh + (size_t)r*1024 + (k - 1024));
    float4 v0 = *reinterpret_cast<const float4*>(s);
    float4 v1 = *reinterpret_cast<const float4*>(s + 4);
    f16x8 o;
    o[0]=(_Float16)v0.x; o[1]=(_Float16)v0.y; o[2]=(_Float16)v0.z; o[3]=(_Float16)v0.w;
    o[4]=(_Float16)v1.x; o[5]=(_Float16)v1.y; o[6]=(_Float16)v1.z; o[7]=(_Float16)v1.w;
    *reinterpret_cast<f16x8*>(Wr + (size_t)p*KCAT + k) = o;
    if (threadIdx.x == 0) br[p] = bx[r] + bh[r];
}

__global__ void prep_x_kernel(const float* __restrict__ x, _Float16* xo){
    size_t i = ((size_t)blockIdx.x*256 + threadIdx.x) * 8;
    float4 v0 = *reinterpret_cast<const float4*>(x + i);
    float4 v1 = *reinterpret_cast<const float4*>(x + i + 4);
    f16x8 o;
    o[0]=(_Float16)v0.x; o[1]=(_Float16)v0.y; o[2]=(_Float16)v0.z; o[3]=(_Float16)v0.w;
    o[4]=(_Float16)v1.x; o[5]=(_Float16)v1.y; o[6]=(_Float16)v1.z; o[7]=(_Float16)v1.w;
    *reinterpret_cast<f16x8*>(xo + i) = o;
}

__global__ void init_flags_kernel(int* flags){
    flags[blockIdx.x*256 + threadIdx.x] = 0;
}

// ---------------- barrier helpers ----------------

__device__ __forceinline__ void bar_store(int* flags, int wg, int ph){
    __hip_atomic_store(&flags[wg*16], ph, __ATOMIC_RELEASE, __HIP_MEMORY_SCOPE_AGENT);
}
__device__ __forceinline__ void bar_wait(const int* flags, int ph, int lane){
    const int b = lane*4;
    for(;;){
        int a0 = __hip_atomic_load(&flags[(b+0)*16], __ATOMIC_RELAXED, __HIP_MEMORY_SCOPE_AGENT);
        int a1 = __hip_atomic_load(&flags[(b+1)*16], __ATOMIC_RELAXED, __HIP_MEMORY_SCOPE_AGENT);
        int a2 = __hip_atomic_load(&flags[(b+2)*16], __ATOMIC_RELAXED, __HIP_MEMORY_SCOPE_AGENT);
        int a3 = __hip_atomic_load(&flags[(b+3)*16], __ATOMIC_RELAXED, __HIP_MEMORY_SCOPE_AGENT);
        bool ok = (a0>=ph) && (a1>=ph) && (a2>=ph) && (a3>=ph);
        if (__all(ok)) break;
        __builtin_amdgcn_s_sleep(2);
    }
    __builtin_amdgcn_fence(__ATOMIC_ACQUIRE, "agent");
}

// ---------------- persistent LSTM kernel ----------------

__global__ __launch_bounds__(256, 1)
void lstm_persist(const _Float16* __restrict__ Wr0, const _Float16* __restrict__ Wr1,
                  const float* __restrict__ br0, const float* __restrict__ br1,
                  const _Float16* xbf, _Float16* hseq0,
                  _Float16* hbuf, float* out, int* flags){
    const int tid  = threadIdx.x;
    const int wg   = blockIdx.x;          // 0..255
    const int wv   = tid >> 6;            // wave 0..3
    const int lane = tid & 63;
    const int r    = lane & 15;           // MFMA row/col-in-tile
    const int q    = lane >> 4;           // k-subgroup 0..3
    const int p0   = wg * 16;             // gate-row base
    const int erow = tid >> 2;            // elementwise: batch row
    const int ejl  = tid & 3;             // elementwise: local h-col
    const int ecol = wg*4 + ejl;          // global h-col

    __shared__ float accLds[4][64][16];   // 16 KB k-partial exchange

    int ph = 1;

    // zero h(t=0) buffer (own columns), then full barrier
    hbuf[(size_t)erow*HID + ecol] = (_Float16)0.f;
    __syncthreads();
    if (tid == 0) bar_store(flags, wg, ph);
    bar_wait(flags, ph, lane);
    ph++;

    for (int layer = 0; layer < 2; ++layer){
        const _Float16* Wr   = layer ? Wr1 : Wr0;
        const float*    br   = layer ? br1 : br0;
        const _Float16* xsrc = layer ? hseq0 : xbf;   // k<1024 operand source
        const f32x4 bias = *reinterpret_cast<const f32x4*>(&br[p0 + ejl*4]);
        float c = 0.f;

        for (int t = 0; t < SEQ; ++t){
            const int cur = t & 1, nxt = cur ^ 1;
            const _Float16* hb_c = hbuf + (size_t)cur*BATCH*HID;

            // ---- GEMM: this wave's K-quarter, 4 m-tiles x 1 n-tile ----
            f32x4 acc[4];
            #pragma unroll
            for (int m = 0; m < 4; ++m){ acc[m].x=0.f; acc[m].y=0.f; acc[m].z=0.f; acc[m].w=0.f; }

            const _Float16* Ab = (wv < 2) ? (xsrc + (size_t)t*BATCH*HID) : hb_c;
            const int kq = (wv & 1) * 512;                 // local k base in region
            const _Float16* Aptr = Ab + (size_t)r*1024 + kq + q*8;
            const _Float16* Wptr = Wr + (size_t)(p0 + r)*KCAT + wv*512 + q*8;

            #pragma unroll 4
            for (int kk = 0; kk < 16; ++kk){
                f16x8 b  = *reinterpret_cast<const f16x8*>(Wptr + kk*32);
                f16x8 a0 = *reinterpret_cast<const f16x8*>(Aptr + kk*32);
                f16x8 a1 = *reinterpret_cast<const f16x8*>(Aptr + kk*32 + 16*1024);
                f16x8 a2 = *reinterpret_cast<const f16x8*>(Aptr + kk*32 + 32*1024);
                f16x8 a3 = *reinterpret_cast<const f16x8*>(Aptr + kk*32 + 48*1024);
                acc[0] = __builtin_amdgcn_mfma_f32_16x16x32_f16(a0, b, acc[0], 0, 0, 0);
                acc[1] = __builtin_amdgcn_mfma_f32_16x16x32_f16(a1, b, acc[1], 0, 0, 0);
                acc[2] = __builtin_amdgcn_mfma_f32_16x16x32_f16(a2, b, acc[2], 0, 0, 0);
                acc[3] = __builtin_amdgcn_mfma_f32_16x16x32_f16(a3, b, acc[3], 0, 0, 0);
            }

            // ---- K-reduction via LDS ----
            #pragma unroll
            for (int mt = 0; mt < 4; ++mt){
                #pragma unroll
                for (int j = 0; j < 4; ++j)
                    accLds[wv][mt*16 + q*4 + j][r] = acc[mt][j];
            }
            __syncthreads();

            // ---- elementwise: this thread owns (erow, ecol) ----
            f32x4 z = bias;
            #pragma unroll
            for (int w2 = 0; w2 < 4; ++w2){
                f32x4 zz = *reinterpret_cast<const f32x4*>(&accLds[w2][erow][ejl*4]);
                z.x += zz.x; z.y += zz.y; z.z += zz.z; z.w += zz.w;
            }
            float ig = sigm_f(z.x);
            float fg = sigm_f(z.y);
            float gg = tanh_f(z.z);
            float og = sigm_f(z.w);
            c = fg*c + ig*gg;
            float h = og * tanh_f(c);
            _Float16 hh = (_Float16)h;

            hbuf[(size_t)nxt*BATCH*HID + (size_t)erow*HID + ecol] = hh;
            if (layer == 0) hseq0[(size_t)t*BATCH*HID + (size_t)erow*HID + ecol] = hh;
            else            out  [(size_t)t*BATCH*HID + (size_t)erow*HID + ecol] = h;

            // ---- step barrier (waves 0/1 never poll: their next-step operand
            //      is t-indexed, not recurrent -> poll hides under their GEMM) ----
            if (t < SEQ-1){
                __syncthreads();                    // drain stores (vmcnt0 before s_barrier)
                if (tid == 0) bar_store(flags, wg, ph);
                if (wv >= 2) bar_wait(flags, ph, lane);
                ph++;
            } else {
                __syncthreads();                    // accLds reuse safety at layer switch
            }
        }

        if (layer == 0){
            // re-zero h for layer 1 (own cols only; disjoint across wgs -> race-free)
            hbuf[(size_t)erow*HID + ecol] = (_Float16)0.f;
            __syncthreads();
            if (tid == 0) bar_store(flags, wg, ph);
            bar_wait(flags, ph, lane);              // full barrier: hseq0 + zeros visible
            ph++;
        }
    }
}

// ---------------- host launcher ----------------

extern "C" void kernel_launch(void* const* d_in, const int* in_sizes, int n_in,
                              void* d_out, int out_size, void* d_ws, size_t ws_size,
                              hipStream_t stream){
    const float* x   = (const float*)d_in[0];
    const float* Wx0 = (const float*)d_in[1];
    const float* bx0 = (const float*)d_in[2];
    const float* Wh0 = (const float*)d_in[3];
    const float* bh0 = (const float*)d_in[4];
    const float* Wx1 = (const float*)d_in[5];
    const float* bx1 = (const float*)d_in[6];
    const float* Wh1 = (const float*)d_in[7];
    const float* bh1 = (const float*)d_in[8];
    float* out = (float*)d_out;
    char* ws = (char*)d_ws;

    size_t o = 0;
    _Float16* Wr0 = (_Float16*)(ws + o); o += (size_t)NG*KCAT*2;      // 16 MB
    _Float16* Wr1 = (_Float16*)(ws + o); o += (size_t)NG*KCAT*2;      // 16 MB
    float* br0 = (float*)(ws + o); o += 16384;
    float* br1 = (float*)(ws + o); o += 16384;
    _Float16* hseq0 = (_Float16*)(ws + o); o += (size_t)SEQ*BATCH*HID*2;  // 64 MB
    _Float16* hbuf  = (_Float16*)(ws + o); o += (size_t)2*BATCH*HID*2;
    int* flags = (int*)(ws + o); o += 16384;
    const size_t need_x = (size_t)SEQ*BATCH*HID*2;                    // 64 MB
    _Float16* xbf;
    if (ws_size >= o + need_x){ xbf = (_Float16*)(ws + o); }
    else                      { xbf = (_Float16*)d_out; }  // d_out scratch: layer1 overwrites after x is dead

    prep_w_kernel<<<NG, 256, 0, stream>>>(Wx0, Wh0, bx0, bh0, Wr0, br0);
    prep_w_kernel<<<NG, 256, 0, stream>>>(Wx1, Wh1, bx1, bh1, Wr1, br1);
    prep_x_kernel<<<(SEQ*BATCH*HID)/(256*8), 256, 0, stream>>>(x, xbf);
    init_flags_kernel<<<16, 256, 0, stream>>>(flags);
    lstm_persist<<<256, 256, 0, stream>>>(Wr0, Wr1, br0, br1, xbf, hseq0, hbuf, out, flags);
}

// Round 3
// 13118.329 us; speedup vs baseline: 1.7352x; 1.7352x over previous
//
#include <hip/hip_runtime.h>
#include <hip/hip_bf16.h>

// LSTM 2-layer, S=512 B=64 IN=H=1024, fp32 I/O, fp16 MFMA compute.
// Persistent kernel, 256 wgs (1/CU) x 256 thr (4 waves).
// R3: fine-grained coherence. h communicated via sc0|sc1 bypass stores into a
// per-step ring (hseq[t], first-touch-after-write => plain cacheable reads are
// safe). NO release/acquire fences anywhere in the step loop => no buffer_wbl2 /
// buffer_inv => weights stay L2-resident. Ordering: h stores -> s_waitcnt
// vmcnt(0) -> relaxed flag store; pollers: relaxed flag loads + compiler barrier.

#define SEQ   512
#define BATCH 64
#define HID   1024
#define NG    4096           // 4*HID
#define KCAT  2048           // IN + HID

typedef __attribute__((ext_vector_type(8))) _Float16 f16x8;
typedef __attribute__((ext_vector_type(4))) _Float16 f16x4;
typedef __attribute__((ext_vector_type(4))) float    f32x4;

__device__ __forceinline__ float sigm_f(float x){ return 1.f/(1.f + __expf(-x)); }
__device__ __forceinline__ float tanh_f(float x){
    float e = __expf(-2.f*fabsf(x));
    float r = (1.f - e)/(1.f + e);
    return copysignf(r, x);
}

// write-through/bypass 8B store (visible at LLC once vmcnt==0)
__device__ __forceinline__ void store_h8(_Float16* p, f16x4 v){
    asm volatile("global_store_dwordx2 %0, %1, off sc0 sc1" :: "v"(p), "v"(v) : "memory");
}

// ---------------- prep kernels ----------------

__global__ void prep_w_kernel(const float* __restrict__ Wx, const float* __restrict__ Wh,
                              const float* __restrict__ bx, const float* __restrict__ bh,
                              _Float16* __restrict__ Wr, float* __restrict__ br){
    int p = blockIdx.x;            // 0..4095 reordered row
    int j = p >> 2, g = p & 3;
    int r = g*1024 + j;            // original row in Wx/Wh
    int k = threadIdx.x * 8;       // 0..2040
    const float* s = (k < 1024) ? (Wx + (size_t)r*1024 + k)
                                : (Wh + (size_t)r*1024 + (k - 1024));
    float4 v0 = *reinterpret_cast<const float4*>(s);
    float4 v1 = *reinterpret_cast<const float4*>(s + 4);
    f16x8 o;
    o[0]=(_Float16)v0.x; o[1]=(_Float16)v0.y; o[2]=(_Float16)v0.z; o[3]=(_Float16)v0.w;
    o[4]=(_Float16)v1.x; o[5]=(_Float16)v1.y; o[6]=(_Float16)v1.z; o[7]=(_Float16)v1.w;
    *reinterpret_cast<f16x8*>(Wr + (size_t)p*KCAT + k) = o;
    if (threadIdx.x == 0) br[p] = bx[r] + bh[r];
}

__global__ void prep_x_kernel(const float* __restrict__ x, _Float16* xo){
    size_t i = ((size_t)blockIdx.x*256 + threadIdx.x) * 8;
    float4 v0 = *reinterpret_cast<const float4*>(x + i);
    float4 v1 = *reinterpret_cast<const float4*>(x + i + 4);
    f16x8 o;
    o[0]=(_Float16)v0.x; o[1]=(_Float16)v0.y; o[2]=(_Float16)v0.z; o[3]=(_Float16)v0.w;
    o[4]=(_Float16)v1.x; o[5]=(_Float16)v1.y; o[6]=(_Float16)v1.z; o[7]=(_Float16)v1.w;
    *reinterpret_cast<f16x8*>(xo + i) = o;
}

__global__ void init_misc_kernel(int* flags, _Float16* hz){
    int i = blockIdx.x*256 + threadIdx.x;            // 16384 threads
    if (i < 8192) flags[i] = 0;                      // 32 KB flag area
    size_t j = (size_t)i * 4;
    if (j < (size_t)BATCH*HID){
        f16x4 z; z[0]=(_Float16)0.f; z[1]=(_Float16)0.f; z[2]=(_Float16)0.f; z[3]=(_Float16)0.f;
        *reinterpret_cast<f16x4*>(hz + j) = z;
    }
}

// ---------------- barrier helpers (no fences!) ----------------

__device__ __forceinline__ void bar_wait(const int* flags, int ph, int lane){
    const int b = lane*4;
    for(;;){
        int a0 = __hip_atomic_load(&flags[(b+0)*32], __ATOMIC_RELAXED, __HIP_MEMORY_SCOPE_AGENT);
        int a1 = __hip_atomic_load(&flags[(b+1)*32], __ATOMIC_RELAXED, __HIP_MEMORY_SCOPE_AGENT);
        int a2 = __hip_atomic_load(&flags[(b+2)*32], __ATOMIC_RELAXED, __HIP_MEMORY_SCOPE_AGENT);
        int a3 = __hip_atomic_load(&flags[(b+3)*32], __ATOMIC_RELAXED, __HIP_MEMORY_SCOPE_AGENT);
        bool ok = (a0>=ph) && (a1>=ph) && (a2>=ph) && (a3>=ph);
        if (__all(ok)) break;
        __builtin_amdgcn_s_sleep(1);
    }
    asm volatile("" ::: "memory");   // compiler barrier: no hoisting ring loads above poll
}

// ---------------- persistent LSTM kernel ----------------

__global__ __launch_bounds__(256, 1)
void lstm_persist(const _Float16* __restrict__ Wr0, const _Float16* __restrict__ Wr1,
                  const float* __restrict__ br0, const float* __restrict__ br1,
                  const _Float16* __restrict__ xbf, const _Float16* __restrict__ hz,
                  _Float16* hseq0, _Float16* hseq1, float* out, int* flags){
    const int tid  = threadIdx.x;
    const int wg   = blockIdx.x;          // 0..255
    const int wv   = tid >> 6;            // wave 0..3
    const int lane = tid & 63;
    const int r    = lane & 15;           // MFMA row/col-in-tile
    const int q    = lane >> 4;           // k-subgroup 0..3
    const int p0   = wg * 16;             // gate-row base

    __shared__ float accLds[2][4][64][17];   // double-buffered, padded (+1)

    for (int layer = 0; layer < 2; ++layer){
        const _Float16* Wr    = layer ? Wr1 : Wr0;
        const float*    br    = layer ? br1 : br0;
        const _Float16* xs    = layer ? hseq0 : xbf;   // k<1024 operand source
        _Float16*       hring = layer ? hseq1 : hseq0;
        const int base = layer * SEQ;
        f32x4 c4 = {0.f, 0.f, 0.f, 0.f};               // cell state (wave 0)

        if (layer == 1){
            bar_wait(flags, SEQ, lane);   // all of layer 0 done: hseq0 complete
            __syncthreads();
        }

        for (int t = 0; t < SEQ; ++t){
            const int par = t & 1;
            if (wv >= 2 && t > 0) bar_wait(flags, base + t, lane);

            // ---- GEMM: this wave's K-quarter, 4 m-tiles x 1 n-tile ----
            f32x4 acc[4];
            #pragma unroll
            for (int m = 0; m < 4; ++m){ acc[m].x=0.f; acc[m].y=0.f; acc[m].z=0.f; acc[m].w=0.f; }

            const _Float16* Ab = (wv < 2) ? (xs + (size_t)t*BATCH*HID)
                                          : (t == 0 ? hz : hring + (size_t)(t-1)*BATCH*HID);
            const int kq = (wv & 1) * 512;
            const _Float16* Aptr = Ab + (size_t)r*1024 + kq + q*8;
            const _Float16* Wptr = Wr + (size_t)(p0 + r)*KCAT + wv*512 + q*8;

            #pragma unroll 4
            for (int kk = 0; kk < 16; ++kk){
                f16x8 b  = *reinterpret_cast<const f16x8*>(Wptr + kk*32);
                f16x8 a0 = *reinterpret_cast<const f16x8*>(Aptr + kk*32);
                f16x8 a1 = *reinterpret_cast<const f16x8*>(Aptr + kk*32 + 16*1024);
                f16x8 a2 = *reinterpret_cast<const f16x8*>(Aptr + kk*32 + 32*1024);
                f16x8 a3 = *reinterpret_cast<const f16x8*>(Aptr + kk*32 + 48*1024);
                acc[0] = __builtin_amdgcn_mfma_f32_16x16x32_f16(a0, b, acc[0], 0, 0, 0);
                acc[1] = __builtin_amdgcn_mfma_f32_16x16x32_f16(a1, b, acc[1], 0, 0, 0);
                acc[2] = __builtin_amdgcn_mfma_f32_16x16x32_f16(a2, b, acc[2], 0, 0, 0);
                acc[3] = __builtin_amdgcn_mfma_f32_16x16x32_f16(a3, b, acc[3], 0, 0, 0);
            }

            // ---- K-partials to LDS ----
            #pragma unroll
            for (int mt = 0; mt < 4; ++mt){
                #pragma unroll
                for (int j = 0; j < 4; ++j)
                    accLds[par][wv][mt*16 + q*4 + j][r] = acc[mt][j];
            }
            __syncthreads();

            // ---- elementwise on wave 0: lane = batch row, 4 h-cols ----
            if (wv == 0){
                f32x4 zz[4];
                #pragma unroll
                for (int jj = 0; jj < 4; ++jj)
                    zz[jj] = *reinterpret_cast<const f32x4*>(&br[p0 + jj*4]);
                #pragma unroll
                for (int w2 = 0; w2 < 4; ++w2){
                    #pragma unroll
                    for (int jj = 0; jj < 4; ++jj){
                        f32x4 a = *reinterpret_cast<const f32x4*>(&accLds[par][w2][lane][jj*4]);
                        zz[jj].x += a.x; zz[jj].y += a.y; zz[jj].z += a.z; zz[jj].w += a.w;
                    }
                }
                f16x4 hv; f32x4 ho;
                #pragma unroll
                for (int jl = 0; jl < 4; ++jl){
                    float ig = sigm_f(zz[jl].x);
                    float fg = sigm_f(zz[jl].y);
                    float gg = tanh_f(zz[jl].z);
                    float og = sigm_f(zz[jl].w);
                    float c  = fg*c4[jl] + ig*gg;
                    c4[jl] = c;
                    float h  = og * tanh_f(c);
                    hv[jl] = (_Float16)h;
                    ho[jl] = h;
                }
                store_h8(hring + ((size_t)t*BATCH + lane)*HID + wg*4, hv);
                asm volatile("s_waitcnt vmcnt(0)" ::: "memory");   // h at LLC
                if (lane == 0)
                    __hip_atomic_store(&flags[wg*32], base + t + 1,
                                       __ATOMIC_RELAXED, __HIP_MEMORY_SCOPE_AGENT);
                if (layer == 1)
                    *reinterpret_cast<f32x4*>(out + ((size_t)t*BATCH + lane)*HID + wg*4) = ho;
            }
        }
    }
}

// ---------------- host launcher ----------------

extern "C" void kernel_launch(void* const* d_in, const int* in_sizes, int n_in,
                              void* d_out, int out_size, void* d_ws, size_t ws_size,
                              hipStream_t stream){
    const float* x   = (const float*)d_in[0];
    const float* Wx0 = (const float*)d_in[1];
    const float* bx0 = (const float*)d_in[2];
    const float* Wh0 = (const float*)d_in[3];
    const float* bh0 = (const float*)d_in[4];
    const float* Wx1 = (const float*)d_in[5];
    const float* bx1 = (const float*)d_in[6];
    const float* Wh1 = (const float*)d_in[7];
    const float* bh1 = (const float*)d_in[8];
    float* out = (float*)d_out;
    char* ws = (char*)d_ws;

    size_t o = 0;
    _Float16* Wr0 = (_Float16*)(ws + o); o += (size_t)NG*KCAT*2;          // 16 MB
    _Float16* Wr1 = (_Float16*)(ws + o); o += (size_t)NG*KCAT*2;          // 16 MB
    float* br0 = (float*)(ws + o); o += 16384;
    float* br1 = (float*)(ws + o); o += 16384;
    _Float16* hseq0 = (_Float16*)(ws + o); o += (size_t)SEQ*BATCH*HID*2;  // 64 MB
    _Float16* hseq1 = (_Float16*)(ws + o); o += (size_t)SEQ*BATCH*HID*2;  // 64 MB
    _Float16* hz    = (_Float16*)(ws + o); o += (size_t)BATCH*HID*2;      // 128 KB
    int* flags = (int*)(ws + o); o += 32768;
    const size_t need_x = (size_t)SEQ*BATCH*HID*2;                        // 64 MB
    _Float16* xbf;
    if (ws_size >= o + need_x){ xbf = (_Float16*)(ws + o); }
    else                      { xbf = (_Float16*)d_out; }  // dead before layer-1 writes out

    prep_w_kernel<<<NG, 256, 0, stream>>>(Wx0, Wh0, bx0, bh0, Wr0, br0);
    prep_w_kernel<<<NG, 256, 0, stream>>>(Wx1, Wh1, bx1, bh1, Wr1, br1);
    prep_x_kernel<<<(SEQ*BATCH*HID)/(256*8), 256, 0, stream>>>(x, xbf);
    init_misc_kernel<<<64, 256, 0, stream>>>(flags, hz);
    lstm_persist<<<256, 256, 0, stream>>>(Wr0, Wr1, br0, br1, xbf, hz, hseq0, hseq1, out, flags);
}